// Round 4
// baseline (99.125 us; speedup 1.0000x reference)
//
#include <hip/hip_runtime.h>
#include <hip/hip_bf16.h>

#define NPTS   300
#define HW_SZ  1920
#define NH     8
#define TOTAL  (NPTS * HW_SZ)    // 576000
#define K      256
#define NCOL   2400              // columns = n*8 + h
#define NPAD   2432              // 38 * 64
#define L2T128 0.10381025293350249f   // log2(10000)/128

typedef __attribute__((ext_vector_type(8))) short short8;
typedef __attribute__((ext_vector_type(4))) float floatx4;

__device__ __forceinline__ unsigned bf16_rne(float x) {
    unsigned u = __float_as_uint(x);
    return (u + 0x7fffu + ((u >> 16) & 1u)) >> 16;
}

// X[hw, i] = cos(k_i * ld(hw)) for i<128 ; X[hw, 128+i] = sin(k_i * ld(hw))
// One thread per (hw, 8-freq segment): 30720 threads.
__global__ __launch_bounds__(256) void build_x(const float* __restrict__ dm,
                                               unsigned short* __restrict__ X)
{
    const int t  = blockIdx.x * 256 + threadIdx.x;   // 0..30719
    const int hw = t >> 4, seg = t & 15;
    const float ld = __logf(dm[hw] + 1e-5f);

    unsigned cp[4], sp[4];
#pragma unroll
    for (int jj = 0; jj < 4; ++jj) {
        const int i0 = seg * 8 + 2 * jj;
        const float k0 = 100.0f * exp2f(-(float)i0 * L2T128);
        const float k1 = 100.0f * exp2f(-(float)(i0 + 1) * L2T128);
        const float a0 = k0 * ld, a1 = k1 * ld;   // |a| <= 1561 rad < 256 rev
        cp[jj] = bf16_rne(__cosf(a0)) | (bf16_rne(__cosf(a1)) << 16);
        sp[jj] = bf16_rne(__sinf(a0)) | (bf16_rne(__sinf(a1)) << 16);
    }
    *(uint4*)(X + (size_t)hw * K + seg * 8)       = make_uint4(cp[0], cp[1], cp[2], cp[3]);
    *(uint4*)(X + (size_t)hw * K + 128 + seg * 8) = make_uint4(sp[0], sp[1], sp[2], sp[3]);
}

// PQt[c, i]     = Ws[i,h]*sin(a) + Wc[i,h]*cos(a)   (P, i<128)
// PQt[c, 128+i] = Wc[i,h]*sin(a) - Ws[i,h]*cos(a)   (Q)
// where a = k_i * lp(n), c = n*8+h. Pad rows c in [2400,2432) are zero.
__global__ __launch_bounds__(256) void build_pqt(const float* __restrict__ pd,
                                                 const float* __restrict__ W,
                                                 unsigned short* __restrict__ PQt)
{
    const int c = blockIdx.x * 256 + threadIdx.x;
    if (c >= NPAD) return;
    unsigned short* row = PQt + (size_t)c * K;
    if (c >= NCOL) {
        const uint4 z = make_uint4(0u, 0u, 0u, 0u);
#pragma unroll
        for (int g = 0; g < K / 8; ++g) ((uint4*)row)[g] = z;
        return;
    }
    const int n = c >> 3, h = c & 7;
    const float lp = __logf(fmaxf(pd[n], 0.0f) + 1e-5f);

    for (int g = 0; g < 16; ++g) {
        unsigned pp[4], qq[4];
#pragma unroll
        for (int jj = 0; jj < 4; ++jj) {
            const int i0 = g * 8 + 2 * jj;
            const float r0 = 100.0f * exp2f(-(float)i0 * L2T128);
            const float r1 = 100.0f * exp2f(-(float)(i0 + 1) * L2T128);
            const float a0 = r0 * lp, a1 = r1 * lp;
            const float s0 = __sinf(a0), co0 = __cosf(a0);
            const float s1 = __sinf(a1), co1 = __cosf(a1);
            const float ws0 = W[i0 * 16 + h],       wc0 = W[i0 * 16 + 8 + h];
            const float ws1 = W[(i0 + 1) * 16 + h], wc1 = W[(i0 + 1) * 16 + 8 + h];
            const float p0 = ws0 * s0 + wc0 * co0, q0 = wc0 * s0 - ws0 * co0;
            const float p1 = ws1 * s1 + wc1 * co1, q1 = wc1 * s1 - ws1 * co1;
            pp[jj] = bf16_rne(p0) | (bf16_rne(p1) << 16);
            qq[jj] = bf16_rne(q0) | (bf16_rne(q1) << 16);
        }
        *(uint4*)(row + g * 8)       = make_uint4(pp[0], pp[1], pp[2], pp[3]);
        *(uint4*)(row + 128 + g * 8) = make_uint4(qq[0], qq[1], qq[2], qq[3]);
    }
}

// OUT[hw, c] = relu( X[hw,:] . PQt[c,:] + b[c&7] ), written to out[h][n][hw].
// Block: 256 thr (4 waves), tile M=128 x N=64, K-chunks of 64, mfma 16x16x32 bf16.
#define BM  128
#define BN  64
#define BK  64
#define LDK 72    // padded LDS k-stride (elements)

__global__ __launch_bounds__(256) void gemm_xpq(const unsigned short* __restrict__ X,
                                                const unsigned short* __restrict__ PQt,
                                                const float* __restrict__ b,
                                                float* __restrict__ out)
{
    __shared__ unsigned short As[BM * LDK];   // 18432 B
    __shared__ unsigned short Bs[BN * LDK];   //  9216 B

    const int tid  = threadIdx.x;
    const int w    = tid >> 6;          // wave 0..3 -> M sub-tile
    const int lane = tid & 63;
    const int quad = lane >> 4;
    const int l16  = lane & 15;
    const int m0   = blockIdx.x * BM;   // hw tile base
    const int c0   = blockIdx.y * BN;   // column tile base

    floatx4 acc[2][4];
#pragma unroll
    for (int mi = 0; mi < 2; ++mi)
#pragma unroll
        for (int nf = 0; nf < 4; ++nf) acc[mi][nf] = (floatx4){0.f, 0.f, 0.f, 0.f};

    for (int k0 = 0; k0 < K; k0 += BK) {
        // stage A: 128 rows x 64 k (16 KB), 4 passes of 256x16B
#pragma unroll
        for (int p = 0; p < 4; ++p) {
            const int row = p * 32 + (tid >> 3);
            const int cg  = (tid & 7) * 8;
            uint4 v = *(const uint4*)(X + (size_t)(m0 + row) * K + k0 + cg);
            *(uint4*)(&As[row * LDK + cg]) = v;
        }
        // stage B (already k-major per column): 64 rows x 64 k (8 KB), 2 passes
#pragma unroll
        for (int p = 0; p < 2; ++p) {
            const int row = p * 32 + (tid >> 3);
            const int cg  = (tid & 7) * 8;
            uint4 v = *(const uint4*)(PQt + (size_t)(c0 + row) * K + k0 + cg);
            *(uint4*)(&Bs[row * LDK + cg]) = v;
        }
        __syncthreads();

#pragma unroll
        for (int ks = 0; ks < 2; ++ks) {
            const int koff = ks * 32 + quad * 8;
            short8 a0 = *(const short8*)(&As[(w * 32 + l16) * LDK + koff]);
            short8 a1 = *(const short8*)(&As[(w * 32 + 16 + l16) * LDK + koff]);
#pragma unroll
            for (int nf = 0; nf < 4; ++nf) {
                short8 bb = *(const short8*)(&Bs[(nf * 16 + l16) * LDK + koff]);
                acc[0][nf] = __builtin_amdgcn_mfma_f32_16x16x32_bf16(a0, bb, acc[0][nf], 0, 0, 0);
                acc[1][nf] = __builtin_amdgcn_mfma_f32_16x16x32_bf16(a1, bb, acc[1][nf], 0, 0, 0);
            }
        }
        __syncthreads();
    }

    // epilogue: C/D layout col=lane&15, row=quad*4+reg  -> rows are hw-contiguous
    const float bias = b[lane & 7];   // col % 8 == lane & 7 (c0, nf*16 multiples of 8)
#pragma unroll
    for (int mi = 0; mi < 2; ++mi) {
#pragma unroll
        for (int nf = 0; nf < 4; ++nf) {
            const int c = c0 + nf * 16 + l16;
            if (c < NCOL) {
                const int n = c >> 3, h = c & 7;
                const int hw = m0 + w * 32 + mi * 16 + quad * 4;
                floatx4 v = acc[mi][nf];
                v.x = fmaxf(v.x + bias, 0.0f);
                v.y = fmaxf(v.y + bias, 0.0f);
                v.z = fmaxf(v.z + bias, 0.0f);
                v.w = fmaxf(v.w + bias, 0.0f);
                *(floatx4*)(out + (size_t)h * TOTAL + (size_t)n * HW_SZ + hw) = v;
            }
        }
    }
}

extern "C" void kernel_launch(void* const* d_in, const int* in_sizes, int n_in,
                              void* d_out, int out_size, void* d_ws, size_t ws_size,
                              hipStream_t stream) {
    const float* pd = (const float*)d_in[0];
    const float* dm = (const float*)d_in[1];
    const float* W  = (const float*)d_in[2];
    const float* b  = (const float*)d_in[3];
    float* out = (float*)d_out;

    unsigned short* X   = (unsigned short*)d_ws;                       // 1920*256*2 = 983 KB
    unsigned short* PQt = (unsigned short*)((char*)d_ws + (1 << 20));  // 2432*256*2 = 1.2 MB

    build_x<<<120, 256, 0, stream>>>(dm, X);
    build_pqt<<<NPAD / 256 + 1, 256, 0, stream>>>(pd, W, PQt);
    gemm_xpq<<<dim3(HW_SZ / BM, NPAD / BN), 256, 0, stream>>>(X, PQt, b, out);
}

// Round 5
// 80.439 us; speedup vs baseline: 1.2323x; 1.2323x over previous
//
#include <hip/hip_runtime.h>
#include <hip/hip_bf16.h>

#define NPTS   300
#define HW_SZ  1920
#define NH     8
#define TOTAL  (NPTS * HW_SZ)    // 576000
#define K      256               // 128 cos || 128 sin
#define NCOL   2400              // columns c = n*8 + h
#define L2T128 0.10381025293350249f   // log2(10000)/128

#define BM  128
#define BN  64
#define BK  64
#define LDK 72                   // padded LDS k-stride (shorts)
#define SNP 132                  // sn/cn padded stride

typedef __attribute__((ext_vector_type(8))) short short8;
typedef __attribute__((ext_vector_type(4))) float floatx4;

__device__ __forceinline__ unsigned bf16_rne(float x) {
    unsigned u = __float_as_uint(x);
    return (u + 0x7fffu + ((u >> 16) & 1u)) >> 16;
}

// out[hw, c] = relu( sum_i Ws[i,h] sin(k_i d) + Wc[i,h] cos(k_i d) + b[h] ),
// d = lp(n) - ld(hw), factorized via angle addition:
//   = relu( sum_i cos(k_i ld)*P[i,c] + sin(k_i ld)*Q[i,c] + b[h] )
//   P = Ws*sin(k lp) + Wc*cos(k lp),  Q = Wc*sin(k lp) - Ws*cos(k lp)
// Single fused kernel: per-block LDS setup + on-the-fly A/B tiles + MFMA.
__global__ __launch_bounds__(256) void dre_fused(const float* __restrict__ pd,
                                                 const float* __restrict__ dm,
                                                 const float* __restrict__ W,
                                                 const float* __restrict__ b,
                                                 float* __restrict__ out)
{
    __shared__ float kf[128];              //  512 B  k_i = 100*10000^(-i/128)
    __shared__ float ldm[BM];              //  512 B  log(dm+eps) per hw row
    __shared__ float sn[8 * SNP];          // 4224 B  sin(k_i * lp(n))
    __shared__ float cn[8 * SNP];          // 4224 B  cos(k_i * lp(n))
    __shared__ float wl[2048];             // 8192 B  W cached (row-major 256x8)
    __shared__ unsigned short As[BM * LDK];// 18432 B
    __shared__ unsigned short Bs[BN * LDK];//  9216 B   => 45.3 KB total, 3 blk/CU

    const int tid  = threadIdx.x;
    const int m0   = blockIdx.x * BM;      // hw tile base
    const int c0   = blockIdx.y * BN;      // column tile base
    const int n0   = c0 >> 3;              // first n of this block's 8

    // ---- setup phase 1: kf, ldm, wl ----
    if (tid < 128) {
        kf[tid] = 100.0f * exp2f(-(float)tid * L2T128);
    } else {
        ldm[tid - 128] = __logf(dm[m0 + tid - 128] + 1e-5f);
    }
    {
        const float4* Wv = (const float4*)W;      // 512 float4s / 256 thr
        *(float4*)&wl[tid * 8]     = Wv[tid * 2];
        *(float4*)&wl[tid * 8 + 4] = Wv[tid * 2 + 1];
    }
    __syncthreads();

    // ---- setup phase 2: sn/cn for the 8 n's (1024 (n,i) pairs, 4/thread) ----
    {
        const int nl = tid >> 5;                  // 0..7
        const int nn = n0 + nl;
        const float pv = (nn < NPTS) ? pd[nn] : 0.0f;   // pad n: masked at store
        const float lp = __logf(fmaxf(pv, 0.0f) + 1e-5f);
#pragma unroll
        for (int j = 0; j < 4; ++j) {
            const int i = (tid & 31) * 4 + j;
            const float a = kf[i] * lp;           // |a| <= 1561 rad < 256 rev
            sn[nl * SNP + i] = __sinf(a);
            cn[nl * SNP + i] = __cosf(a);
        }
    }

    const int w    = tid >> 6;         // wave -> M sub-tile
    const int lane = tid & 63;
    const int quad = lane >> 4;
    const int l16  = lane & 15;

    floatx4 acc[2][4];
#pragma unroll
    for (int mi = 0; mi < 2; ++mi)
#pragma unroll
        for (int nf = 0; nf < 4; ++nf) acc[mi][nf] = (floatx4){0.f, 0.f, 0.f, 0.f};

    // A-staging constants: thread -> (row, 32-wide k group)
    const int arow = tid >> 1;
    const int akb  = (tid & 1) * 32;
    // B-staging constants: thread -> (c row, 16-wide k group)
    const int bc   = tid & 63;
    const int bnl  = bc >> 3;
    const int bh   = bc & 7;
    const int bkb  = (tid >> 6) * 16;

    __syncthreads();   // sn/cn ready

    for (int k0 = 0; k0 < K; k0 += BK) {
        const bool isSin = (k0 >= 128);
        const int  ibase = k0 & 64;        // freq index base of this chunk

        // ---- stage A chunk: As[row][kk] = trig(kf[ibase+akb+kk] * ldm[row]) ----
        {
            const float ld = ldm[arow];
            uint4 u[4];
            unsigned* uw = (unsigned*)u;
#pragma unroll
            for (int g = 0; g < 16; ++g) {
                const int i = ibase + akb + g * 2;
                const float a0 = kf[i] * ld;
                const float a1 = kf[i + 1] * ld;
                const float v0 = isSin ? __sinf(a0) : __cosf(a0);
                const float v1 = isSin ? __sinf(a1) : __cosf(a1);
                uw[g] = bf16_rne(v0) | (bf16_rne(v1) << 16);
            }
#pragma unroll
            for (int g = 0; g < 4; ++g)
                *(uint4*)&As[arow * LDK + akb + g * 8] = u[g];
        }
        // ---- stage B chunk: Bs[c][kk] = P or Q (from cached sn/cn, wl) ----
        {
            uint4 u[2];
            unsigned* uw = (unsigned*)u;
#pragma unroll
            for (int g = 0; g < 8; ++g) {
                const int i = ibase + bkb + g * 2;
                const float s0 = sn[bnl * SNP + i],     c0v = cn[bnl * SNP + i];
                const float s1 = sn[bnl * SNP + i + 1], c1v = cn[bnl * SNP + i + 1];
                const float ws0 = wl[i * 16 + bh],        wc0 = wl[i * 16 + 8 + bh];
                const float ws1 = wl[(i + 1) * 16 + bh],  wc1 = wl[(i + 1) * 16 + 8 + bh];
                const float v0 = isSin ? (wc0 * s0 - ws0 * c0v) : (ws0 * s0 + wc0 * c0v);
                const float v1 = isSin ? (wc1 * s1 - ws1 * c1v) : (ws1 * s1 + wc1 * c1v);
                uw[g] = bf16_rne(v0) | (bf16_rne(v1) << 16);
            }
            *(uint4*)&Bs[bc * LDK + bkb]     = u[0];
            *(uint4*)&Bs[bc * LDK + bkb + 8] = u[1];
        }
        __syncthreads();

        // ---- MFMA on the 64-wide chunk (identical to R4's verified core) ----
#pragma unroll
        for (int ks = 0; ks < 2; ++ks) {
            const int koff = ks * 32 + quad * 8;
            short8 a0 = *(const short8*)(&As[(w * 32 + l16) * LDK + koff]);
            short8 a1 = *(const short8*)(&As[(w * 32 + 16 + l16) * LDK + koff]);
#pragma unroll
            for (int nf = 0; nf < 4; ++nf) {
                short8 bb = *(const short8*)(&Bs[(nf * 16 + l16) * LDK + koff]);
                acc[0][nf] = __builtin_amdgcn_mfma_f32_16x16x32_bf16(a0, bb, acc[0][nf], 0, 0, 0);
                acc[1][nf] = __builtin_amdgcn_mfma_f32_16x16x32_bf16(a1, bb, acc[1][nf], 0, 0, 0);
            }
        }
        __syncthreads();
    }

    // ---- epilogue (R4-verified): C/D col=lane&15, row=quad*4+reg ----
    const float bias = b[lane & 7];
#pragma unroll
    for (int mi = 0; mi < 2; ++mi) {
#pragma unroll
        for (int nf = 0; nf < 4; ++nf) {
            const int c = c0 + nf * 16 + l16;
            if (c < NCOL) {
                const int n = c >> 3, h = c & 7;
                const int hw = m0 + w * 32 + mi * 16 + quad * 4;
                floatx4 v = acc[mi][nf];
                v.x = fmaxf(v.x + bias, 0.0f);
                v.y = fmaxf(v.y + bias, 0.0f);
                v.z = fmaxf(v.z + bias, 0.0f);
                v.w = fmaxf(v.w + bias, 0.0f);
                *(floatx4*)(out + (size_t)h * TOTAL + (size_t)n * HW_SZ + hw) = v;
            }
        }
    }
}

extern "C" void kernel_launch(void* const* d_in, const int* in_sizes, int n_in,
                              void* d_out, int out_size, void* d_ws, size_t ws_size,
                              hipStream_t stream) {
    const float* pd = (const float*)d_in[0];
    const float* dm = (const float*)d_in[1];
    const float* W  = (const float*)d_in[2];
    const float* b  = (const float*)d_in[3];
    float* out = (float*)d_out;

    dre_fused<<<dim3(HW_SZ / BM, (NCOL + BN - 1) / BN), 256, 0, stream>>>(pd, dm, W, b, out);
}

// Round 7
// 79.522 us; speedup vs baseline: 1.2465x; 1.0115x over previous
//
#include <hip/hip_runtime.h>
#include <hip/hip_bf16.h>

#define NPTS   300
#define HW_SZ  1920
#define NH     8
#define TOTAL  (NPTS * HW_SZ)    // 576000
#define NCOL   2400              // columns c = n*8 + h
#define L2T128 0.10381025293350249f   // log2(10000)/128

#define BM  128
#define BN  128
#define LDK 72                   // padded LDS k-stride (shorts)
#define SNP 129                  // sn/cn padded stride (floats)
#define MT  (HW_SZ / BM)         // 15
#define CT  19                   // ceil(2400/128), pad to 2432

typedef __attribute__((ext_vector_type(8))) short short8;
typedef __attribute__((ext_vector_type(4))) float floatx4;

__device__ __forceinline__ unsigned bf16_rne(float x) {
    unsigned u = __float_as_uint(x);
    return (u + 0x7fffu + ((u >> 16) & 1u)) >> 16;
}

// out[hw, c] = relu( sum_i cos(k_i ld)*P[i,c] + sin(k_i ld)*Q[i,c] + b[h] )
//   P = Ws*sin(k lp) + Wc*cos(k lp),  Q = Wc*sin(k lp) - Ws*cos(k lp)
// Fused: per-block trig + P/Q build into LDS, MFMA GEMM (K=256: 128 cos || 128 sin).
__global__ __launch_bounds__(256, 2) void dre_fused2(const float* __restrict__ pd,
                                                     const float* __restrict__ dm,
                                                     const float* __restrict__ W,
                                                     const float* __restrict__ b,
                                                     float* __restrict__ out)
{
    __shared__ float kf[128];               //  0.5 KB
    __shared__ float ldm[BM];               //  0.5 KB
    __shared__ float sn[16 * SNP];          //  8.1 KB  sin(k_i lp(n)), 16 n's
    __shared__ float cn[16 * SNP];          //  8.1 KB
    __shared__ float wl[2048];              //  8.2 KB  W cached
    __shared__ unsigned short As[BM * LDK]; // 18.4 KB
    __shared__ unsigned short Bs[BN * LDK]; // 18.4 KB   => ~62 KB, 2 blk/CU

    const int tid = threadIdx.x;
    const int m0  = blockIdx.x * BM;
    const int c0  = blockIdx.y * BN;
    const int n0  = c0 >> 3;                // 16 n's per block

    // ---- setup: kf, ldm, wl ----
    if (tid < 128) kf[tid] = 100.0f * exp2f(-(float)tid * L2T128);
    else           ldm[tid - 128] = __logf(dm[m0 + tid - 128] + 1e-5f);
    {
        const float4* Wv = (const float4*)W;
        *(float4*)&wl[tid * 8]     = Wv[tid * 2];
        *(float4*)&wl[tid * 8 + 4] = Wv[tid * 2 + 1];
    }
    __syncthreads();

    // ---- sn/cn for 16 n's (16 threads per n, 8 freqs each) ----
    {
        const int nl = tid >> 4;
        const int nn = n0 + nl;
        const float pv = (nn < NPTS) ? pd[nn] : 0.0f;  // pad n masked at store
        const float lp = __logf(fmaxf(pv, 0.0f) + 1e-5f);
#pragma unroll
        for (int j = 0; j < 8; ++j) {
            const int i = (tid & 15) * 8 + j;
            float s, c;
            __sincosf(kf[i] * lp, &s, &c);             // |a| <= 1561 rad < 256 rev
            sn[nl * SNP + i] = s;
            cn[nl * SNP + i] = c;
        }
    }

    const int w    = tid >> 6;
    const int lane = tid & 63;
    const int quad = lane >> 4;
    const int l16  = lane & 15;

    const int arow = tid >> 1;              // A staging: row, 32-wide k half
    const int akb  = (tid & 1) * 32;
    const int bc   = tid & 127;             // B staging: c row, 32-wide k half
    const int bnl  = bc >> 3;
    const int bh   = bc & 7;
    const int bkb  = (tid >> 7) * 32;

    floatx4 acc[2][8];
#pragma unroll
    for (int mi = 0; mi < 2; ++mi)
#pragma unroll
        for (int nf = 0; nf < 8; ++nf) acc[mi][nf] = (floatx4){0.f, 0.f, 0.f, 0.f};

    unsigned stash[2][16];                  // packed sin for chunks 2/3

    __syncthreads();

    // K-chunks: ch 0,1 = cos(k_i ld) i in [0,64),[64,128); ch 2,3 = sin, same i.
#pragma unroll
    for (int ch = 0; ch < 4; ++ch) {
        const int ibase = (ch & 1) * 64;
        // ---- A tile ----
        if (ch < 2) {
            const float ld = ldm[arow];
            unsigned uc[16];
#pragma unroll
            for (int g = 0; g < 16; ++g) {
                const int i = ibase + akb + 2 * g;
                float s0, c0v, s1, c1v;
                __sincosf(kf[i] * ld,     &s0, &c0v);
                __sincosf(kf[i + 1] * ld, &s1, &c1v);
                uc[g]        = bf16_rne(c0v) | (bf16_rne(c1v) << 16);
                stash[ch][g] = bf16_rne(s0)  | (bf16_rne(s1)  << 16);
            }
#pragma unroll
            for (int g4 = 0; g4 < 4; ++g4)
                *(uint4*)&As[arow * LDK + akb + g4 * 8] =
                    make_uint4(uc[g4*4], uc[g4*4+1], uc[g4*4+2], uc[g4*4+3]);
        } else {
#pragma unroll
            for (int g4 = 0; g4 < 4; ++g4)
                *(uint4*)&As[arow * LDK + akb + g4 * 8] =
                    make_uint4(stash[ch-2][g4*4],   stash[ch-2][g4*4+1],
                               stash[ch-2][g4*4+2], stash[ch-2][g4*4+3]);
        }
        // ---- B tile (P for ch<2, Q for ch>=2) ----
        {
            unsigned uq[16];
#pragma unroll
            for (int g = 0; g < 16; ++g) {
                const int i = ibase + bkb + 2 * g;
                const float s0  = sn[bnl * SNP + i],     cc0 = cn[bnl * SNP + i];
                const float s1  = sn[bnl * SNP + i + 1], cc1 = cn[bnl * SNP + i + 1];
                const float ws0 = wl[i * 16 + bh],       wc0 = wl[i * 16 + 8 + bh];
                const float ws1 = wl[(i+1) * 16 + bh],   wc1 = wl[(i+1) * 16 + 8 + bh];
                float v0, v1;
                if (ch < 2) { v0 = ws0*s0 + wc0*cc0; v1 = ws1*s1 + wc1*cc1; }
                else        { v0 = wc0*s0 - ws0*cc0; v1 = wc1*s1 - ws1*cc1; }
                uq[g] = bf16_rne(v0) | (bf16_rne(v1) << 16);
            }
#pragma unroll
            for (int g4 = 0; g4 < 4; ++g4)
                *(uint4*)&Bs[bc * LDK + bkb + g4 * 8] =
                    make_uint4(uq[g4*4], uq[g4*4+1], uq[g4*4+2], uq[g4*4+3]);
        }
        __syncthreads();

        // ---- MFMA (R4/R5-verified core, nf widened to 8) ----
#pragma unroll
        for (int ks = 0; ks < 2; ++ks) {
            const int koff = ks * 32 + quad * 8;
            short8 a0 = *(const short8*)(&As[(w * 32 + l16) * LDK + koff]);
            short8 a1 = *(const short8*)(&As[(w * 32 + 16 + l16) * LDK + koff]);
#pragma unroll
            for (int nf = 0; nf < 8; ++nf) {
                short8 bb = *(const short8*)(&Bs[(nf * 16 + l16) * LDK + koff]);
                acc[0][nf] = __builtin_amdgcn_mfma_f32_16x16x32_bf16(a0, bb, acc[0][nf], 0, 0, 0);
                acc[1][nf] = __builtin_amdgcn_mfma_f32_16x16x32_bf16(a1, bb, acc[1][nf], 0, 0, 0);
            }
        }
        __syncthreads();
    }

    // ---- epilogue (verified): C/D col=lane&15, row=quad*4+reg ----
    const float bias = b[lane & 7];
#pragma unroll
    for (int mi = 0; mi < 2; ++mi) {
#pragma unroll
        for (int nf = 0; nf < 8; ++nf) {
            const int c = c0 + nf * 16 + l16;
            if (c < NCOL) {
                const int n = c >> 3, h = c & 7;
                const int hw = m0 + w * 32 + mi * 16 + quad * 4;
                floatx4 v = acc[mi][nf];
                v.x = fmaxf(v.x + bias, 0.0f);
                v.y = fmaxf(v.y + bias, 0.0f);
                v.z = fmaxf(v.z + bias, 0.0f);
                v.w = fmaxf(v.w + bias, 0.0f);
                *(floatx4*)(out + (size_t)h * TOTAL + (size_t)n * HW_SZ + hw) = v;
            }
        }
    }
}

extern "C" void kernel_launch(void* const* d_in, const int* in_sizes, int n_in,
                              void* d_out, int out_size, void* d_ws, size_t ws_size,
                              hipStream_t stream) {
    const float* pd = (const float*)d_in[0];
    const float* dm = (const float*)d_in[1];
    const float* W  = (const float*)d_in[2];
    const float* b  = (const float*)d_in[3];
    float* out = (float*)d_out;

    dre_fused2<<<dim3(MT, CT), 256, 0, stream>>>(pd, dm, W, b, out);
}